// Round 2
// baseline (2464.664 us; speedup 1.0000x reference)
//
#include <hip/hip_runtime.h>
#include <hip/hip_bf16.h>
#include <math.h>

// ---------- helpers ----------
__device__ __forceinline__ unsigned enc_f(float f) {
    unsigned b = __float_as_uint(f);
    return b ^ ((b & 0x80000000u) ? 0xFFFFFFFFu : 0x80000000u);
}
__device__ __forceinline__ float dec_f(unsigned u) {
    return __uint_as_float(u ^ ((u & 0x80000000u) ? 0x80000000u : 0xFFFFFFFFu));
}
__device__ __forceinline__ void fma4(float (&a)[4], float s, const float4 w) {
    a[0] = fmaf(s, w.x, a[0]); a[1] = fmaf(s, w.y, a[1]);
    a[2] = fmaf(s, w.z, a[2]); a[3] = fmaf(s, w.w, a[3]);
}
__device__ __forceinline__ float bf2f(unsigned short u) {
    return __uint_as_float(((unsigned)u) << 16);
}
__device__ __forceinline__ unsigned short f2bf(float f) {
    unsigned u = __float_as_uint(f);
    return (unsigned short)((u + 0x7FFFu + ((u >> 16) & 1u)) >> 16);
}

// ---------- K1: node projections q,k,v (bf16 -> ws) and skip (fp32 -> out) ----------
// block = 256 threads, tile = 64 nodes x 512 cols (4 matrices x 128)
__global__ __launch_bounds__(256) void k_node_proj(
    const float* __restrict__ x,
    const float* __restrict__ Wq, const float* __restrict__ bq,
    const float* __restrict__ Wk, const float* __restrict__ bk,
    const float* __restrict__ Wv, const float* __restrict__ bv,
    const float* __restrict__ Wsk, const float* __restrict__ bsk,
    unsigned short* __restrict__ qa, unsigned short* __restrict__ ka,
    unsigned short* __restrict__ va,
    float* __restrict__ outp, int nN)
{
    __shared__ float xs[128][64];   // transposed x tile [k][n], 32 KB
    const int t = threadIdx.x;
    const int n0 = blockIdx.x * 64;
    #pragma unroll
    for (int r = 0; r < 8; ++r) {
        int f4 = t + 256 * r;            // 2048 float4 = 64 nodes * 128
        int n  = f4 >> 5;
        int k  = (f4 & 31) << 2;
        float4 xv = make_float4(0.f, 0.f, 0.f, 0.f);
        if (n0 + n < nN) xv = *(const float4*)(x + (size_t)(n0 + n) * 128 + k);
        xs[k + 0][n] = xv.x; xs[k + 1][n] = xv.y;
        xs[k + 2][n] = xv.z; xs[k + 3][n] = xv.w;
    }
    __syncthreads();

    const int cg  = t & 127;             // col group: cols cg*4 .. cg*4+3 of 512
    const int nb  = (t >> 7) * 32;       // node sub-block
    const int mat = cg >> 5;             // 0=q 1=k 2=v 3=skip
    const int cm  = (cg & 31) * 4;       // col within matrix
    const float* W = (mat == 0) ? Wq : (mat == 1) ? Wk : (mat == 2) ? Wv : Wsk;
    const float* B = (mat == 0) ? bq : (mat == 1) ? bk : (mat == 2) ? bv : bsk;

    float acc[32][4] = {};
    for (int k = 0; k < 128; ++k) {
        const float4 w = *(const float4*)(W + k * 128 + cm);
        #pragma unroll
        for (int i = 0; i < 32; i += 4) {
            const float4 xv = *(const float4*)&xs[k][nb + i];
            fma4(acc[i + 0], xv.x, w);
            fma4(acc[i + 1], xv.y, w);
            fma4(acc[i + 2], xv.z, w);
            fma4(acc[i + 3], xv.w, w);
        }
    }
    const float4 b4 = *(const float4*)(B + cm);
    if (mat == 3) {
        #pragma unroll
        for (int i = 0; i < 32; ++i) {
            int n = n0 + nb + i;
            if (n < nN) {
                float4 r = make_float4(acc[i][0] + b4.x, acc[i][1] + b4.y,
                                       acc[i][2] + b4.z, acc[i][3] + b4.w);
                *(float4*)(outp + (size_t)n * 128 + cm) = r;
            }
        }
    } else {
        unsigned short* D = (mat == 0) ? qa : (mat == 1) ? ka : va;
        #pragma unroll
        for (int i = 0; i < 32; ++i) {
            int n = n0 + nb + i;
            if (n < nN) {
                ushort4 r;
                r.x = f2bf(acc[i][0] + b4.x); r.y = f2bf(acc[i][1] + b4.y);
                r.z = f2bf(acc[i][2] + b4.z); r.w = f2bf(acc[i][3] + b4.w);
                *(ushort4*)(D + (size_t)n * 128 + cm) = r;
            }
        }
    }
}

// ---------- K2: per-edge alpha + segment max ----------
// block = 256, tile = 32 edges; We staged in LDS; thread = 4 cols x 4 edges
__global__ __launch_bounds__(256) void k_edge_alpha(
    const float* __restrict__ lu, const float* __restrict__ tt,
    const float* __restrict__ msg,
    const int* __restrict__ src, const int* __restrict__ dst,
    const float* __restrict__ tw, const float* __restrict__ tb,
    const float* __restrict__ We,
    const unsigned short* __restrict__ qa, const unsigned short* __restrict__ ka,
    float* __restrict__ alpha, unsigned* __restrict__ mmax,
    int nE, int nTiles)
{
    __shared__ float WeS[96][128];   // 48 KB
    __shared__ float attr[96][32];   // 12 KB, [feature][edge]
    const int t = threadIdx.x;
    #pragma unroll
    for (int r = 0; r < 12; ++r) {
        int f4 = t + 256 * r;        // 3072 float4 = 96*128
        int j = f4 >> 5, c = (f4 & 31) << 2;
        *(float4*)&WeS[j][c] = *(const float4*)(We + j * 128 + c);
    }
    __syncthreads();

    const int cg = t & 31;   // cols cg*4..+3
    const int eg = t >> 5;   // edges eg*4..+3

    for (int tile = blockIdx.x; tile < nTiles; tile += gridDim.x) {
        const int e0 = tile * 32;
        {   // time encoding -> attr[0..31]
            int el = t & 31, jq = t >> 5;
            int e = e0 + el;
            if (e < nE) {
                float rel = lu[src[e]] - tt[e];
                #pragma unroll
                for (int i = 0; i < 4; ++i) {
                    int j = jq * 4 + i;
                    attr[j][el] = __cosf(fmaf(rel, tw[j], tb[j]));
                }
            }
        }
        {   // msg -> attr[32..95]
            int el = t >> 3, q8 = t & 7;
            int e = e0 + el;
            if (e < nE) {
                const float4 a0 = *(const float4*)(msg + (size_t)e * 64 + q8 * 8);
                const float4 a1 = *(const float4*)(msg + (size_t)e * 64 + q8 * 8 + 4);
                attr[32 + q8 * 8 + 0][el] = a0.x; attr[32 + q8 * 8 + 1][el] = a0.y;
                attr[32 + q8 * 8 + 2][el] = a0.z; attr[32 + q8 * 8 + 3][el] = a0.w;
                attr[32 + q8 * 8 + 4][el] = a1.x; attr[32 + q8 * 8 + 5][el] = a1.y;
                attr[32 + q8 * 8 + 6][el] = a1.z; attr[32 + q8 * 8 + 7][el] = a1.w;
            }
        }
        __syncthreads();

        float acc[4][4] = {};     // e-matmul accum [edge][col]
        #pragma unroll 4
        for (int j = 0; j < 96; ++j) {
            const float4 w  = *(const float4*)&WeS[j][cg * 4];
            const float4 av = *(const float4*)&attr[j][eg * 4];
            fma4(acc[0], av.x, w); fma4(acc[1], av.y, w);
            fma4(acc[2], av.z, w); fma4(acc[3], av.w, w);
        }

        #pragma unroll
        for (int ei = 0; ei < 4; ++ei) {
            const int e = e0 + eg * 4 + ei;
            if (e < nE) {
                const int d = dst[e], s = src[e];
                const ushort4 q4 = *(const ushort4*)(qa + (size_t)d * 128 + cg * 4);
                const ushort4 k4 = *(const ushort4*)(ka + (size_t)s * 128 + cg * 4);
                float p = bf2f(q4.x) * (bf2f(k4.x) + acc[ei][0])
                        + bf2f(q4.y) * (bf2f(k4.y) + acc[ei][1])
                        + bf2f(q4.z) * (bf2f(k4.z) + acc[ei][2])
                        + bf2f(q4.w) * (bf2f(k4.w) + acc[ei][3]);
                p += __shfl_xor(p, 1);
                p += __shfl_xor(p, 2);
                p += __shfl_xor(p, 4);
                p += __shfl_xor(p, 8);
                if ((cg & 15) == 0) {
                    const float al = p * 0.125f;   // / sqrt(64)
                    const int h = cg >> 4;
                    alpha[(size_t)e * 2 + h] = al;
                    atomicMax(mmax + (size_t)d * 2 + h, enc_f(al));
                }
            }
        }
        __syncthreads();
    }
}

// ---------- K3: softmax denominator ----------
__global__ __launch_bounds__(256) void k_denom(
    const float* __restrict__ alpha, const int* __restrict__ dst,
    const unsigned* __restrict__ mmax, float* __restrict__ denom, int n2)
{
    int i = blockIdx.x * 256 + threadIdx.x;
    if (i < n2) {
        int e = i >> 1, h = i & 1;
        int d = dst[e];
        float m = dec_f(mmax[(size_t)d * 2 + h]);
        atomicAdd(denom + (size_t)d * 2 + h, __expf(alpha[i] - m));
    }
}

// ---------- K4: recompute e, weighted scatter-add ----------
__global__ __launch_bounds__(256) void k_edge_out(
    const float* __restrict__ lu, const float* __restrict__ tt,
    const float* __restrict__ msg,
    const int* __restrict__ src, const int* __restrict__ dst,
    const float* __restrict__ tw, const float* __restrict__ tb,
    const float* __restrict__ We,
    const unsigned short* __restrict__ va, const float* __restrict__ alpha,
    const unsigned* __restrict__ mmax, const float* __restrict__ denom,
    float* __restrict__ outp, int nE, int nTiles)
{
    __shared__ float WeS[96][128];
    __shared__ float attr[96][32];
    const int t = threadIdx.x;
    #pragma unroll
    for (int r = 0; r < 12; ++r) {
        int f4 = t + 256 * r;
        int j = f4 >> 5, c = (f4 & 31) << 2;
        *(float4*)&WeS[j][c] = *(const float4*)(We + j * 128 + c);
    }
    __syncthreads();

    const int cg = t & 31;
    const int eg = t >> 5;

    for (int tile = blockIdx.x; tile < nTiles; tile += gridDim.x) {
        const int e0 = tile * 32;
        {
            int el = t & 31, jq = t >> 5;
            int e = e0 + el;
            if (e < nE) {
                float rel = lu[src[e]] - tt[e];
                #pragma unroll
                for (int i = 0; i < 4; ++i) {
                    int j = jq * 4 + i;
                    attr[j][el] = __cosf(fmaf(rel, tw[j], tb[j]));
                }
            }
        }
        {
            int el = t >> 3, q8 = t & 7;
            int e = e0 + el;
            if (e < nE) {
                const float4 a0 = *(const float4*)(msg + (size_t)e * 64 + q8 * 8);
                const float4 a1 = *(const float4*)(msg + (size_t)e * 64 + q8 * 8 + 4);
                attr[32 + q8 * 8 + 0][el] = a0.x; attr[32 + q8 * 8 + 1][el] = a0.y;
                attr[32 + q8 * 8 + 2][el] = a0.z; attr[32 + q8 * 8 + 3][el] = a0.w;
                attr[32 + q8 * 8 + 4][el] = a1.x; attr[32 + q8 * 8 + 5][el] = a1.y;
                attr[32 + q8 * 8 + 6][el] = a1.z; attr[32 + q8 * 8 + 7][el] = a1.w;
            }
        }
        __syncthreads();

        float acc[4][4] = {};
        #pragma unroll 4
        for (int j = 0; j < 96; ++j) {
            const float4 w  = *(const float4*)&WeS[j][cg * 4];
            const float4 av = *(const float4*)&attr[j][eg * 4];
            fma4(acc[0], av.x, w); fma4(acc[1], av.y, w);
            fma4(acc[2], av.z, w); fma4(acc[3], av.w, w);
        }

        #pragma unroll
        for (int ei = 0; ei < 4; ++ei) {
            const int e = e0 + eg * 4 + ei;
            if (e < nE) {
                const int d = dst[e], s = src[e];
                const ushort4 v4 = *(const ushort4*)(va + (size_t)s * 128 + cg * 4);
                const int h = cg >> 4;
                const float m = dec_f(mmax[(size_t)d * 2 + h]);
                const float a = __expf(alpha[(size_t)e * 2 + h] - m)
                              / (denom[(size_t)d * 2 + h] + 1e-16f);
                float* op = outp + (size_t)d * 128 + cg * 4;
                atomicAdd(op + 0, (bf2f(v4.x) + acc[ei][0]) * a);
                atomicAdd(op + 1, (bf2f(v4.y) + acc[ei][1]) * a);
                atomicAdd(op + 2, (bf2f(v4.z) + acc[ei][2]) * a);
                atomicAdd(op + 3, (bf2f(v4.w) + acc[ei][3]) * a);
            }
        }
        __syncthreads();
    }
}

// ---------- launch ----------
extern "C" void kernel_launch(void* const* d_in, const int* in_sizes, int n_in,
                              void* d_out, int out_size, void* d_ws, size_t ws_size,
                              hipStream_t stream) {
    const float* x   = (const float*)d_in[0];
    const float* lu  = (const float*)d_in[1];
    const float* tt  = (const float*)d_in[2];
    const float* msg = (const float*)d_in[3];
    const int*   ei  = (const int*)d_in[4];
    const float* tw  = (const float*)d_in[5];
    const float* tb  = (const float*)d_in[6];
    const float* Wq  = (const float*)d_in[7];
    const float* bq  = (const float*)d_in[8];
    const float* Wk  = (const float*)d_in[9];
    const float* bk  = (const float*)d_in[10];
    const float* Wv  = (const float*)d_in[11];
    const float* bv  = (const float*)d_in[12];
    const float* We  = (const float*)d_in[13];
    const float* Wsk = (const float*)d_in[14];
    const float* bsk = (const float*)d_in[15];

    const int N = in_sizes[1];        // 100000
    const int E = in_sizes[2];        // 800000
    const int* src = ei;
    const int* dst = ei + E;
    float* out = (float*)d_out;

    // workspace layout: q,k,v bf16 [N*128] each, alpha fp32 [E*2],
    // mmax u32 [N*2], denom fp32 [N*2]   (~85 MB total at N=100k, E=800k)
    unsigned short* qa = (unsigned short*)d_ws;
    unsigned short* ka = qa + (size_t)N * 128;
    unsigned short* va = ka + (size_t)N * 128;
    float*    alpha = (float*)(va + (size_t)N * 128);
    unsigned* mmax  = (unsigned*)(alpha + (size_t)E * 2);
    float*    denom = (float*)(mmax + (size_t)N * 2);

    // zero segment-max (monotone-mapped: 0 acts as -inf) and denominators
    hipMemsetAsync(mmax, 0, (size_t)N * 4 * sizeof(float), stream);

    const int nTiles = (E + 31) / 32;
    const int g1 = (N + 63) / 64;
    const int g2 = (nTiles < 2048) ? nTiles : 2048;
    const int g3 = (2 * E + 255) / 256;

    k_node_proj<<<g1, 256, 0, stream>>>(x, Wq, bq, Wk, bk, Wv, bv, Wsk, bsk,
                                        qa, ka, va, out, N);
    k_edge_alpha<<<g2, 256, 0, stream>>>(lu, tt, msg, src, dst, tw, tb, We,
                                         qa, ka, alpha, mmax, E, nTiles);
    k_denom<<<g3, 256, 0, stream>>>(alpha, dst, mmax, denom, 2 * E);
    k_edge_out<<<g2, 256, 0, stream>>>(lu, tt, msg, src, dst, tw, tb, We,
                                       va, alpha, mmax, denom, out, E, nTiles);
}

// Round 3
// 1583.348 us; speedup vs baseline: 1.5566x; 1.5566x over previous
//
#include <hip/hip_runtime.h>
#include <hip/hip_bf16.h>
#include <math.h>

// ---------- helpers ----------
__device__ __forceinline__ void fma4(float (&a)[4], float s, const float4 w) {
    a[0] = fmaf(s, w.x, a[0]); a[1] = fmaf(s, w.y, a[1]);
    a[2] = fmaf(s, w.z, a[2]); a[3] = fmaf(s, w.w, a[3]);
}
__device__ __forceinline__ float bf2f(unsigned short u) {
    return __uint_as_float(((unsigned)u) << 16);
}
__device__ __forceinline__ unsigned short f2bf(float f) {
    unsigned u = __float_as_uint(f);
    return (unsigned short)((u + 0x7FFFu + ((u >> 16) & 1u)) >> 16);
}

// ---------- K1: node projections q,k,v (bf16 -> ws) and skip (fp32 -> out) ----------
// block = 256 threads, tile = 64 nodes x 512 cols (4 matrices x 128)
__global__ __launch_bounds__(256) void k_node_proj(
    const float* __restrict__ x,
    const float* __restrict__ Wq, const float* __restrict__ bq,
    const float* __restrict__ Wk, const float* __restrict__ bk,
    const float* __restrict__ Wv, const float* __restrict__ bv,
    const float* __restrict__ Wsk, const float* __restrict__ bsk,
    unsigned short* __restrict__ qa, unsigned short* __restrict__ ka,
    unsigned short* __restrict__ va,
    float* __restrict__ outp, int nN)
{
    __shared__ float xs[128][64];   // transposed x tile [k][n], 32 KB
    const int t = threadIdx.x;
    const int n0 = blockIdx.x * 64;
    #pragma unroll
    for (int r = 0; r < 8; ++r) {
        int f4 = t + 256 * r;            // 2048 float4 = 64 nodes * 128
        int n  = f4 >> 5;
        int k  = (f4 & 31) << 2;
        float4 xv = make_float4(0.f, 0.f, 0.f, 0.f);
        if (n0 + n < nN) xv = *(const float4*)(x + (size_t)(n0 + n) * 128 + k);
        xs[k + 0][n] = xv.x; xs[k + 1][n] = xv.y;
        xs[k + 2][n] = xv.z; xs[k + 3][n] = xv.w;
    }
    __syncthreads();

    const int cg  = t & 127;             // col group: cols cg*4 .. cg*4+3 of 512
    const int nb  = (t >> 7) * 32;       // node sub-block
    const int mat = cg >> 5;             // 0=q 1=k 2=v 3=skip
    const int cm  = (cg & 31) * 4;       // col within matrix
    const float* W = (mat == 0) ? Wq : (mat == 1) ? Wk : (mat == 2) ? Wv : Wsk;
    const float* B = (mat == 0) ? bq : (mat == 1) ? bk : (mat == 2) ? bv : bsk;

    float acc[32][4] = {};
    for (int k = 0; k < 128; ++k) {
        const float4 w = *(const float4*)(W + k * 128 + cm);
        #pragma unroll
        for (int i = 0; i < 32; i += 4) {
            const float4 xv = *(const float4*)&xs[k][nb + i];
            fma4(acc[i + 0], xv.x, w);
            fma4(acc[i + 1], xv.y, w);
            fma4(acc[i + 2], xv.z, w);
            fma4(acc[i + 3], xv.w, w);
        }
    }
    const float4 b4 = *(const float4*)(B + cm);
    if (mat == 3) {
        #pragma unroll
        for (int i = 0; i < 32; ++i) {
            int n = n0 + nb + i;
            if (n < nN) {
                float4 r = make_float4(acc[i][0] + b4.x, acc[i][1] + b4.y,
                                       acc[i][2] + b4.z, acc[i][3] + b4.w);
                *(float4*)(outp + (size_t)n * 128 + cm) = r;
            }
        }
    } else {
        unsigned short* D = (mat == 0) ? qa : (mat == 1) ? ka : va;
        #pragma unroll
        for (int i = 0; i < 32; ++i) {
            int n = n0 + nb + i;
            if (n < nN) {
                ushort4 r;
                r.x = f2bf(acc[i][0] + b4.x); r.y = f2bf(acc[i][1] + b4.y);
                r.z = f2bf(acc[i][2] + b4.z); r.w = f2bf(acc[i][3] + b4.w);
                *(ushort4*)(D + (size_t)n * 128 + cm) = r;
            }
        }
    }
}

// ---------- CSR build ----------
__global__ __launch_bounds__(256) void k_hist(
    const int* __restrict__ dst, int* __restrict__ deg, int nE)
{
    int e = blockIdx.x * 256 + threadIdx.x;
    if (e < nE) atomicAdd(&deg[dst[e]], 1);
}

__global__ __launch_bounds__(256) void k_rowptr(
    const int* __restrict__ deg, int* __restrict__ start,
    int* __restrict__ cur, int* __restrict__ cursor, int nN)
{
    int n = blockIdx.x * 256 + threadIdx.x;
    if (n < nN) {
        int d = deg[n];
        int s = atomicAdd(cursor, d);
        start[n] = s;
        cur[n] = s;
    }
}

__global__ __launch_bounds__(256) void k_scatter(
    const int* __restrict__ dst, int* __restrict__ cur,
    int* __restrict__ eid, int nE)
{
    int e = blockIdx.x * 256 + threadIdx.x;
    if (e < nE) {
        int p = atomicAdd(&cur[dst[e]], 1);
        eid[p] = e;
    }
}

// ---------- K2: fused per-destination attention ----------
// one wave per dst node; We staged fp32 in LDS (48 KB); lane owns 2 cols.
// online softmax in registers; single non-atomic output store.
__global__ __launch_bounds__(256) void k_attn_fused(
    const float* __restrict__ lu, const float* __restrict__ tt,
    const float* __restrict__ msg,
    const int* __restrict__ src,
    const float* __restrict__ tw, const float* __restrict__ tb,
    const float* __restrict__ We,
    const unsigned short* __restrict__ qa, const unsigned short* __restrict__ ka,
    const unsigned short* __restrict__ va,
    const int* __restrict__ start, const int* __restrict__ deg,
    const int* __restrict__ eid,
    float* __restrict__ outp, int nN)
{
    __shared__ float WeS[96][128];            // 48 KB
    __shared__ float attr[4][96];             // per-wave attr buffer
    const int t = threadIdx.x;
    #pragma unroll
    for (int r = 0; r < 12; ++r) {
        int f4 = t + 256 * r;                 // 3072 float4 = 96*128
        int j = f4 >> 5, c = (f4 & 31) << 2;
        *(float4*)&WeS[j][c] = *(const float4*)(We + j * 128 + c);
    }
    __syncthreads();

    const int lane = t & 63;
    const int w    = t >> 6;
    const int gw   = blockIdx.x * 4 + w;
    const int nw   = gridDim.x * 4;
    float* at = attr[w];
    const float twl = (lane < 32) ? tw[lane] : 0.f;
    const float tbl = (lane < 32) ? tb[lane] : 0.f;

    for (int n = gw; n < nN; n += nw) {
        const int s0 = start[n];
        const int d  = deg[n];

        float q0, q1;
        {
            ushort2 q2 = *(const ushort2*)(qa + (size_t)n * 128 + lane * 2);
            q0 = bf2f(q2.x); q1 = bf2f(q2.y);
        }
        float m = -INFINITY, den = 0.f, o0 = 0.f, o1 = 0.f;

        for (int base = 0; base < d; base += 64) {
            const int cnt = min(64, d - base);
            int eL = 0, sL = 0;
            if (lane < cnt) {
                eL = eid[s0 + base + lane];
                sL = src[eL];
            }
            // prefetch edge 0 of chunk
            int   e_cur = __shfl(eL, 0);
            int   s_cur = __shfl(sL, 0);
            float ms_n  = msg[(size_t)e_cur * 64 + lane];
            float rel_n = lu[s_cur] - tt[e_cur];

            for (int i = 0; i < cnt; ++i) {
                const int   e   = e_cur;
                const int   se  = s_cur;
                const float ms  = ms_n;
                const float rel = rel_n;
                if (i + 1 < cnt) {           // prefetch next edge
                    e_cur = __shfl(eL, i + 1);
                    s_cur = __shfl(sL, i + 1);
                    ms_n  = msg[(size_t)e_cur * 64 + lane];
                    rel_n = lu[s_cur] - tt[e_cur];
                }
                // stage attr (wave-local LDS, no barrier needed)
                at[32 + lane] = ms;
                if (lane < 32) at[lane] = __cosf(fmaf(rel, twl, tbl));

                // gather k,v for current edge (needed only after j-loop)
                const ushort2 k2 = *(const ushort2*)(ka + (size_t)se * 128 + lane * 2);
                const ushort2 v2 = *(const ushort2*)(va + (size_t)se * 128 + lane * 2);

                // e = attr @ We, 2 cols per lane; msg part first (ready sooner)
                float e0 = 0.f, e1 = 0.f;
                #pragma unroll 8
                for (int j = 32; j < 96; ++j) {
                    const float aj = at[j];
                    const float2 w2 = *(const float2*)&WeS[j][lane * 2];
                    e0 = fmaf(aj, w2.x, e0);
                    e1 = fmaf(aj, w2.y, e1);
                }
                #pragma unroll 8
                for (int j = 0; j < 32; ++j) {
                    const float aj = at[j];
                    const float2 w2 = *(const float2*)&WeS[j][lane * 2];
                    e0 = fmaf(aj, w2.x, e0);
                    e1 = fmaf(aj, w2.y, e1);
                }

                // alpha = q . (k+e) / sqrt(64), reduced per 32-lane head
                float p = q0 * (bf2f(k2.x) + e0) + q1 * (bf2f(k2.y) + e1);
                p += __shfl_xor(p, 1);
                p += __shfl_xor(p, 2);
                p += __shfl_xor(p, 4);
                p += __shfl_xor(p, 8);
                p += __shfl_xor(p, 16);
                const float al = p * 0.125f;

                // online softmax
                const float mo = m;
                m = fmaxf(m, al);
                const float cs  = (mo == -INFINITY) ? 0.f : __expf(mo - m);
                const float wgt = __expf(al - m);
                den = den * cs + wgt;
                o0  = o0 * cs + wgt * (bf2f(v2.x) + e0);
                o1  = o1 * cs + wgt * (bf2f(v2.y) + e1);
            }
        }

        const float inv = 1.f / (den + 1e-16f);
        float2 sk = *(const float2*)(outp + (size_t)n * 128 + lane * 2);
        sk.x += o0 * inv;
        sk.y += o1 * inv;
        *(float2*)(outp + (size_t)n * 128 + lane * 2) = sk;
    }
}

// ---------- launch ----------
extern "C" void kernel_launch(void* const* d_in, const int* in_sizes, int n_in,
                              void* d_out, int out_size, void* d_ws, size_t ws_size,
                              hipStream_t stream) {
    const float* x   = (const float*)d_in[0];
    const float* lu  = (const float*)d_in[1];
    const float* tt  = (const float*)d_in[2];
    const float* msg = (const float*)d_in[3];
    const int*   ei  = (const int*)d_in[4];
    const float* tw  = (const float*)d_in[5];
    const float* tb  = (const float*)d_in[6];
    const float* Wq  = (const float*)d_in[7];
    const float* bq  = (const float*)d_in[8];
    const float* Wk  = (const float*)d_in[9];
    const float* bk  = (const float*)d_in[10];
    const float* Wv  = (const float*)d_in[11];
    const float* bv  = (const float*)d_in[12];
    const float* We  = (const float*)d_in[13];
    const float* Wsk = (const float*)d_in[14];
    const float* bsk = (const float*)d_in[15];

    const int N = in_sizes[1];        // 100000
    const int E = in_sizes[2];        // 800000
    const int* src = ei;
    const int* dst = ei + E;
    float* out = (float*)d_out;

    // workspace layout: q,k,v bf16 [N*128] each (~77 MB),
    // then CSR: start[N], deg[N], cursor[1], cur[N], eid[E]  (ints)
    unsigned short* qa = (unsigned short*)d_ws;
    unsigned short* ka = qa + (size_t)N * 128;
    unsigned short* va = ka + (size_t)N * 128;
    int* start  = (int*)(va + (size_t)N * 128);
    int* deg    = start + N;
    int* cursor = deg + N;
    int* cur    = cursor + 1;
    int* eid    = cur + N;

    // zero degree histogram + cursor
    hipMemsetAsync(deg, 0, (size_t)(N + 1) * sizeof(int), stream);

    const int gE = (E + 255) / 256;
    const int gN = (N + 255) / 256;
    const int g1 = (N + 63) / 64;

    k_node_proj<<<g1, 256, 0, stream>>>(x, Wq, bq, Wk, bk, Wv, bv, Wsk, bsk,
                                        qa, ka, va, out, N);
    k_hist<<<gE, 256, 0, stream>>>(dst, deg, E);
    k_rowptr<<<gN, 256, 0, stream>>>(deg, start, cur, cursor, N);
    k_scatter<<<gE, 256, 0, stream>>>(dst, cur, eid, E);
    k_attn_fused<<<2048, 256, 0, stream>>>(lu, tt, msg, src, tw, tb, We,
                                           qa, ka, va, start, deg, eid, out, N);
}

// Round 4
// 1007.926 us; speedup vs baseline: 2.4453x; 1.5709x over previous
//
#include <hip/hip_runtime.h>
#include <hip/hip_bf16.h>
#include <math.h>

// ---------- helpers ----------
__device__ __forceinline__ void fma4(float (&a)[4], float s, const float4 w) {
    a[0] = fmaf(s, w.x, a[0]); a[1] = fmaf(s, w.y, a[1]);
    a[2] = fmaf(s, w.z, a[2]); a[3] = fmaf(s, w.w, a[3]);
}
__device__ __forceinline__ float bf2f(unsigned short u) {
    return __uint_as_float(((unsigned)u) << 16);
}
__device__ __forceinline__ unsigned short f2bf(float f) {
    unsigned u = __float_as_uint(f);
    return (unsigned short)((u + 0x7FFFu + ((u >> 16) & 1u)) >> 16);
}

// ---------- K1: node projections q,k,v (bf16 -> ws) and skip (fp32 -> out) ----------
__global__ __launch_bounds__(256) void k_node_proj(
    const float* __restrict__ x,
    const float* __restrict__ Wq, const float* __restrict__ bq,
    const float* __restrict__ Wk, const float* __restrict__ bk,
    const float* __restrict__ Wv, const float* __restrict__ bv,
    const float* __restrict__ Wsk, const float* __restrict__ bsk,
    unsigned short* __restrict__ qa, unsigned short* __restrict__ ka,
    unsigned short* __restrict__ va,
    float* __restrict__ outp, int nN)
{
    __shared__ float xs[128][64];   // transposed x tile [k][n], 32 KB
    const int t = threadIdx.x;
    const int n0 = blockIdx.x * 64;
    #pragma unroll
    for (int r = 0; r < 8; ++r) {
        int f4 = t + 256 * r;            // 2048 float4 = 64 nodes * 128
        int n  = f4 >> 5;
        int k  = (f4 & 31) << 2;
        float4 xv = make_float4(0.f, 0.f, 0.f, 0.f);
        if (n0 + n < nN) xv = *(const float4*)(x + (size_t)(n0 + n) * 128 + k);
        xs[k + 0][n] = xv.x; xs[k + 1][n] = xv.y;
        xs[k + 2][n] = xv.z; xs[k + 3][n] = xv.w;
    }
    __syncthreads();

    const int cg  = t & 127;
    const int nb  = (t >> 7) * 32;
    const int mat = cg >> 5;             // 0=q 1=k 2=v 3=skip
    const int cm  = (cg & 31) * 4;
    const float* W = (mat == 0) ? Wq : (mat == 1) ? Wk : (mat == 2) ? Wv : Wsk;
    const float* B = (mat == 0) ? bq : (mat == 1) ? bk : (mat == 2) ? bv : bsk;

    float acc[32][4] = {};
    for (int k = 0; k < 128; ++k) {
        const float4 w = *(const float4*)(W + k * 128 + cm);
        #pragma unroll
        for (int i = 0; i < 32; i += 4) {
            const float4 xv = *(const float4*)&xs[k][nb + i];
            fma4(acc[i + 0], xv.x, w);
            fma4(acc[i + 1], xv.y, w);
            fma4(acc[i + 2], xv.z, w);
            fma4(acc[i + 3], xv.w, w);
        }
    }
    const float4 b4 = *(const float4*)(B + cm);
    if (mat == 3) {
        #pragma unroll
        for (int i = 0; i < 32; ++i) {
            int n = n0 + nb + i;
            if (n < nN) {
                float4 r = make_float4(acc[i][0] + b4.x, acc[i][1] + b4.y,
                                       acc[i][2] + b4.z, acc[i][3] + b4.w);
                *(float4*)(outp + (size_t)n * 128 + cm) = r;
            }
        }
    } else {
        unsigned short* D = (mat == 0) ? qa : (mat == 1) ? ka : va;
        #pragma unroll
        for (int i = 0; i < 32; ++i) {
            int n = n0 + nb + i;
            if (n < nN) {
                ushort4 r;
                r.x = f2bf(acc[i][0] + b4.x); r.y = f2bf(acc[i][1] + b4.y);
                r.z = f2bf(acc[i][2] + b4.z); r.w = f2bf(acc[i][3] + b4.w);
                *(ushort4*)(D + (size_t)n * 128 + cm) = r;
            }
        }
    }
}

// ---------- k_u: U[n][h*96+j] = sum_c We[j][64h+c] * q[n][64h+c]  (bf16 out) ----------
// block = 192 threads (thread = jh), tile = 64 nodes; q tile staged fp32 in LDS.
__global__ __launch_bounds__(192) void k_u(
    const unsigned short* __restrict__ qa, const float* __restrict__ We,
    unsigned short* __restrict__ U, int nN)
{
    __shared__ float qs[64][132];       // 33.8 KB, padded
    const int t = threadIdx.x;
    const int n0 = blockIdx.x * 64;
    for (int r = 0; r < 11; ++r) {
        int f4 = t + 192 * r;           // 2048 ushort4 = 64 nodes * 32
        if (f4 < 2048) {
            int n = f4 >> 5, k4 = (f4 & 31) << 2;
            ushort4 v = make_ushort4(0, 0, 0, 0);
            if (n0 + n < nN) v = *(const ushort4*)(qa + (size_t)(n0 + n) * 128 + k4);
            qs[n][k4 + 0] = bf2f(v.x); qs[n][k4 + 1] = bf2f(v.y);
            qs[n][k4 + 2] = bf2f(v.z); qs[n][k4 + 3] = bf2f(v.w);
        }
    }
    __syncthreads();

    const int j = t % 96;
    const int h = t / 96;
    float wr[64];
    #pragma unroll
    for (int c = 0; c < 64; ++c) wr[c] = We[(size_t)j * 128 + 64 * h + c];

    for (int n = 0; n < 64; ++n) {
        float acc = 0.f;
        #pragma unroll
        for (int ci = 0; ci < 16; ++ci) {
            const float4 qv = *(const float4*)&qs[n][64 * h + ci * 4];
            acc = fmaf(wr[ci * 4 + 0], qv.x, acc);
            acc = fmaf(wr[ci * 4 + 1], qv.y, acc);
            acc = fmaf(wr[ci * 4 + 2], qv.z, acc);
            acc = fmaf(wr[ci * 4 + 3], qv.w, acc);
        }
        if (n0 + n < nN) U[(size_t)(n0 + n) * 192 + t] = f2bf(acc);
    }
}

// ---------- CSR build ----------
__global__ __launch_bounds__(256) void k_hist(
    const int* __restrict__ dst, int* __restrict__ deg, int nE)
{
    int e = blockIdx.x * 256 + threadIdx.x;
    if (e < nE) atomicAdd(&deg[dst[e]], 1);
}
__global__ __launch_bounds__(256) void k_rowptr(
    const int* __restrict__ deg, int* __restrict__ start,
    int* __restrict__ cur, int* __restrict__ cursor, int nN)
{
    int n = blockIdx.x * 256 + threadIdx.x;
    if (n < nN) {
        int d = deg[n];
        int s = atomicAdd(cursor, d);
        start[n] = s;
        cur[n] = s;
    }
}
__global__ __launch_bounds__(256) void k_scatter(
    const int* __restrict__ dst, int* __restrict__ cur,
    int* __restrict__ eid, int nE)
{
    int e = blockIdx.x * 256 + threadIdx.x;
    if (e < nE) {
        int p = atomicAdd(&cur[dst[e]], 1);
        eid[p] = e;
    }
}

// ---------- k_attn2: fused per-dst attention with factored We ----------
// wave per node. alpha = (q.k + attr.U[dst])/8 via 64-lane butterfly.
// online softmax keeps o (v-part) and s = sum a*attr; finish: out += (o + s@We)/den.
__global__ __launch_bounds__(256) void k_attn2(
    const float* __restrict__ lu, const float* __restrict__ tt,
    const float* __restrict__ msg,
    const int* __restrict__ src,
    const float* __restrict__ tw, const float* __restrict__ tb,
    const float* __restrict__ We,
    const unsigned short* __restrict__ qa, const unsigned short* __restrict__ ka,
    const unsigned short* __restrict__ va, const unsigned short* __restrict__ U,
    const int* __restrict__ start, const int* __restrict__ deg,
    const int* __restrict__ eid,
    float* __restrict__ outp, int nN)
{
    __shared__ unsigned WeS[96][64];    // bf16x2 pairs, 24 KB: col pair p = lane
    __shared__ float sS[4][192];        // per-wave s staging
    const int t = threadIdx.x;
    #pragma unroll
    for (int r = 0; r < 12; ++r) {
        int f4 = t + 256 * r;           // 3072 float4 = 96*32 pairs-of-2
        int j = f4 >> 5, c = (f4 & 31) << 2;
        const float4 w = *(const float4*)(We + (size_t)j * 128 + c);
        WeS[j][(c >> 1) + 0] = (unsigned)f2bf(w.x) | ((unsigned)f2bf(w.y) << 16);
        WeS[j][(c >> 1) + 1] = (unsigned)f2bf(w.z) | ((unsigned)f2bf(w.w) << 16);
    }
    __syncthreads();

    const int lane = t & 63;
    const int w    = t >> 6;
    const int gw   = blockIdx.x * 4 + w;
    const int nw   = gridDim.x * 4;
    const bool lo32 = (lane < 32);
    const int h    = lane >> 5;
    const float twl = tw[lane & 31];
    const float tbl = tb[lane & 31];

    for (int n = gw; n < nN; n += nw) {
        const int d = deg[n];
        if (d == 0) continue;
        const int s0 = start[n];

        float q0, q1;
        {
            ushort2 q2 = *(const ushort2*)(qa + (size_t)n * 128 + lane * 2);
            q0 = bf2f(q2.x); q1 = bf2f(q2.y);
        }
        const unsigned short* Un = U + (size_t)n * 192;
        const float uc0 = bf2f(Un[lane & 31]);
        const float um0 = bf2f(Un[32 + lane]);
        const float uc1 = bf2f(Un[96 + (lane & 31)]);
        const float um1 = bf2f(Un[128 + lane]);

        float m = -INFINITY, den = 0.f, o0 = 0.f, o1 = 0.f;
        float sc0 = 0.f, sc1 = 0.f, sm0 = 0.f, sm1 = 0.f;

        for (int base = 0; base < d; base += 64) {
            const int cnt = min(64, d - base);
            int eL = 0, sL = 0;
            if (lane < cnt) {
                eL = eid[s0 + base + lane];
                sL = src[eL];
            }
            // prefetch edge 0
            int e_n = __shfl(eL, 0), s_n = __shfl(sL, 0);
            float  ms_n = msg[(size_t)e_n * 64 + lane];
            ushort2 k_n = *(const ushort2*)(ka + (size_t)s_n * 128 + lane * 2);
            ushort2 v_n = *(const ushort2*)(va + (size_t)s_n * 128 + lane * 2);
            float  lu_n = lu[s_n], tt_n = tt[e_n];

            for (int i = 0; i < cnt; ++i) {
                const float   ms  = ms_n;
                const ushort2 k2  = k_n;
                const ushort2 v2  = v_n;
                const float   rel = lu_n - tt_n;
                if (i + 1 < cnt) {
                    e_n = __shfl(eL, i + 1); s_n = __shfl(sL, i + 1);
                    ms_n = msg[(size_t)e_n * 64 + lane];
                    k_n  = *(const ushort2*)(ka + (size_t)s_n * 128 + lane * 2);
                    v_n  = *(const ushort2*)(va + (size_t)s_n * 128 + lane * 2);
                    lu_n = lu[s_n]; tt_n = tt[e_n];
                }

                float cv = __cosf(fmaf(rel, twl, tbl));
                cv = lo32 ? cv : 0.f;
                const float qk = q0 * bf2f(k2.x) + q1 * bf2f(k2.y);
                float z0 = fmaf(cv, uc0, ms * um0) + (lo32 ? qk : 0.f);
                float z1 = fmaf(cv, uc1, ms * um1) + (lo32 ? 0.f : qk);
                #pragma unroll
                for (int off = 1; off < 64; off <<= 1) {
                    z0 += __shfl_xor(z0, off);
                    z1 += __shfl_xor(z1, off);
                }
                const float al = 0.125f * (lo32 ? z0 : z1);

                const float mo = m;
                m = fmaxf(m, al);
                const float cs  = __expf(mo - m);     // 0 on first edge
                const float wgt = __expf(al - m);
                const float csx = __shfl_xor(cs, 32);
                const float wx  = __shfl_xor(wgt, 32);
                const float cs0 = lo32 ? cs : csx, cs1 = lo32 ? csx : cs;
                const float w0  = lo32 ? wgt : wx, w1  = lo32 ? wx : wgt;

                den = fmaf(den, cs, wgt);
                o0  = fmaf(o0, cs, wgt * bf2f(v2.x));
                o1  = fmaf(o1, cs, wgt * bf2f(v2.y));
                sc0 = fmaf(sc0, cs0, w0 * cv);
                sc1 = fmaf(sc1, cs1, w1 * cv);
                sm0 = fmaf(sm0, cs0, w0 * ms);
                sm1 = fmaf(sm1, cs1, w1 * ms);
            }
        }

        // stage s into per-wave LDS (layout: [h*96 + j], j<32 = cos, j>=32 = msg)
        sS[w][32 + lane]  = sm0;
        sS[w][128 + lane] = sm1;
        if (lo32) { sS[w][lane] = sc0; sS[w][96 + lane] = sc1; }

        const float inv = 1.f / (den + 1e-16f);
        float e0 = 0.f, e1 = 0.f;
        #pragma unroll 8
        for (int j = 0; j < 96; ++j) {
            const float sj = sS[w][h * 96 + j];
            const unsigned wp = WeS[j][lane];
            e0 = fmaf(sj, __uint_as_float(wp << 16), e0);
            e1 = fmaf(sj, __uint_as_float(wp & 0xffff0000u), e1);
        }
        float2 sk = *(float2*)(outp + (size_t)n * 128 + lane * 2);
        sk.x += (o0 + e0) * inv;
        sk.y += (o1 + e1) * inv;
        *(float2*)(outp + (size_t)n * 128 + lane * 2) = sk;
    }
}

// ---------- launch ----------
extern "C" void kernel_launch(void* const* d_in, const int* in_sizes, int n_in,
                              void* d_out, int out_size, void* d_ws, size_t ws_size,
                              hipStream_t stream) {
    const float* x   = (const float*)d_in[0];
    const float* lu  = (const float*)d_in[1];
    const float* tt  = (const float*)d_in[2];
    const float* msg = (const float*)d_in[3];
    const int*   ei  = (const int*)d_in[4];
    const float* tw  = (const float*)d_in[5];
    const float* tb  = (const float*)d_in[6];
    const float* Wq  = (const float*)d_in[7];
    const float* bq  = (const float*)d_in[8];
    const float* Wk  = (const float*)d_in[9];
    const float* bk  = (const float*)d_in[10];
    const float* Wv  = (const float*)d_in[11];
    const float* bv  = (const float*)d_in[12];
    const float* We  = (const float*)d_in[13];
    const float* Wsk = (const float*)d_in[14];
    const float* bsk = (const float*)d_in[15];

    const int N = in_sizes[1];        // 100000
    const int E = in_sizes[2];        // 800000
    const int* src = ei;
    const int* dst = ei + E;
    float* out = (float*)d_out;

    // ws: qkv bf16 [N*128]x3 (77MB), U bf16 [N*192] (38MB), CSR ints (~8MB)
    unsigned short* qa = (unsigned short*)d_ws;
    unsigned short* ka = qa + (size_t)N * 128;
    unsigned short* va = ka + (size_t)N * 128;
    unsigned short* U  = va + (size_t)N * 128;
    int* start  = (int*)(U + (size_t)N * 192);
    int* deg    = start + N;
    int* cursor = deg + N;
    int* cur    = cursor + 1;
    int* eid    = cur + N;

    hipMemsetAsync(deg, 0, (size_t)(N + 1) * sizeof(int), stream);

    const int gE = (E + 255) / 256;
    const int gN = (N + 255) / 256;
    const int g64 = (N + 63) / 64;

    k_node_proj<<<g64, 256, 0, stream>>>(x, Wq, bq, Wk, bk, Wv, bv, Wsk, bsk,
                                         qa, ka, va, out, N);
    k_hist<<<gE, 256, 0, stream>>>(dst, deg, E);
    k_rowptr<<<gN, 256, 0, stream>>>(deg, start, cur, cursor, N);
    k_scatter<<<gE, 256, 0, stream>>>(dst, cur, eid, E);
    k_u<<<g64, 192, 0, stream>>>(qa, We, U, N);
    k_attn2<<<2048, 256, 0, stream>>>(lu, tt, msg, src, tw, tb, We,
                                      qa, ka, va, U, start, deg, eid, out, N);
}